// Round 4
// baseline (194.397 us; speedup 1.0000x reference)
//
#include <hip/hip_runtime.h>
#include <hip/hip_bf16.h>
#include <math.h>

#define N_TOK 8192
#define D_IN  768
#define D_OUT 64
#define WAVES 8
#define KVB   32

typedef __attribute__((ext_vector_type(8))) short short8;
typedef __attribute__((ext_vector_type(4))) short short4v;
typedef __attribute__((ext_vector_type(4))) float f32x4;

// f32 -> bf16 bits, round-to-nearest-even
__device__ __forceinline__ short f2bf(float f) {
  union { float f; unsigned u; } v; v.f = f;
  unsigned r = v.u + 0x7fffu + ((v.u >> 16) & 1u);
  return (short)(r >> 16);
}
__device__ __forceinline__ unsigned pack2(float lo, float hi) {
  return (unsigned)(unsigned short)f2bf(lo) | ((unsigned)(unsigned short)f2bf(hi) << 16);
}

// ---------------------------------------------------------------------------
// Projection (R1 structure: grid (N/64, 3), one output per blockIdx.y).
//   which==0: Q, pre-scaled by log2(e)/8; which==1: K; which==2: Vt[d][n]
// ---------------------------------------------------------------------------
__global__ __launch_bounds__(256) void proj_kernel(
    const float* __restrict__ X,
    const float* __restrict__ Wq, const float* __restrict__ Wk,
    const float* __restrict__ Wv,
    short* __restrict__ Q, short* __restrict__ K, short* __restrict__ Vt)
{
  __shared__ short Xs[64][40];
  __shared__ short Ws[64][40];   // W^T tile: [col][k]

  const int t  = threadIdx.x;
  const int w  = t >> 6;
  const int l  = t & 63;
  const int g  = l >> 4;
  const int lr = l & 15;
  const int which = blockIdx.y;
  const float* W = (which == 0) ? Wq : (which == 1) ? Wk : Wv;
  const int r0 = blockIdx.x * 64;

  f32x4 acc[4] = {};

  for (int kb = 0; kb < D_IN; kb += 32) {
    {
      const int row = t >> 2, kc = (t & 3) * 8;
      const float* src = X + (size_t)(r0 + row) * D_IN + kb + kc;
      short8 v;
      #pragma unroll
      for (int i = 0; i < 8; ++i) v[i] = f2bf(src[i]);
      *reinterpret_cast<short8*>(&Xs[row][kc]) = v;
    }
    {
      const int col = t & 63, k0 = (t >> 6) * 8;
      #pragma unroll
      for (int i = 0; i < 8; ++i)
        Ws[col][k0 + i] = f2bf(W[(size_t)(kb + k0 + i) * D_OUT + col]);
    }
    __syncthreads();

    short8 a = *reinterpret_cast<const short8*>(&Xs[w * 16 + lr][g * 8]);
    #pragma unroll
    for (int dt = 0; dt < 4; ++dt) {
      short8 b = *reinterpret_cast<const short8*>(&Ws[dt * 16 + lr][g * 8]);
      acc[dt] = __builtin_amdgcn_mfma_f32_16x16x32_bf16(a, b, acc[dt], 0, 0, 0);
    }
    __syncthreads();
  }

  const int rb = r0 + w * 16 + g * 4;
  if (which == 0) {
    const float QS = 0.18033688011112042f;  // log2(e) / sqrt(64)
    #pragma unroll
    for (int dt = 0; dt < 4; ++dt)
      #pragma unroll
      for (int r = 0; r < 4; ++r)
        Q[(size_t)(rb + r) * D_OUT + dt * 16 + lr] = f2bf(acc[dt][r] * QS);
  } else if (which == 1) {
    #pragma unroll
    for (int dt = 0; dt < 4; ++dt)
      #pragma unroll
      for (int r = 0; r < 4; ++r)
        K[(size_t)(rb + r) * D_OUT + dt * 16 + lr] = f2bf(acc[dt][r]);
  } else {
    #pragma unroll
    for (int dt = 0; dt < 4; ++dt) {
      short4v pv;
      #pragma unroll
      for (int r = 0; r < 4; ++r) pv[r] = f2bf(acc[dt][r]);
      *reinterpret_cast<short4v*>(&Vt[(size_t)(dt * 16 + lr) * N_TOK + rb]) = pv;
    }
  }
}

// ---------------------------------------------------------------------------
// Flash attention, swapped operands + k-slot permutation:
//   S = mfma(K,Q): lane holds S[kv in regs][q = lane&15]
//   kv->k-slot map: slot g*8+j  <->  kv g*4+j (j<4) / 16+g*4+(j-4) (j>=4)
//   => P's C-layout registers ARE the PV B-fragment after bf16 packing:
//      no LDS, no cross-lane ops anywhere in the steady-state loop.
//   Vt A-frags use the same permutation: two 8B loads per dt.
// 2-deep manual K prefetch (unroll-by-2, named frag sets).
// ---------------------------------------------------------------------------
__global__ __launch_bounds__(512, 4) void attn_kernel(
    const short* __restrict__ Q, const short* __restrict__ K,
    const short* __restrict__ Vt, float* __restrict__ out)
{
  __shared__ float Opart[WAVES][16][68];
  __shared__ float mpart[WAVES][16];
  __shared__ float lpart[WAVES][16];

  const int t  = threadIdx.x;
  const int w  = t >> 6;
  const int l  = t & 63;
  const int g  = l >> 4;
  const int lr = l & 15;
  const int q0 = blockIdx.x * 16;

  const short* qp = Q + (size_t)(q0 + lr) * D_OUT + g * 8;
  short8 aq0 = *reinterpret_cast<const short8*>(qp);
  short8 aq1 = *reinterpret_cast<const short8*>(qp + 32);

  float m = -INFINITY, lsum = 0.0f;
  f32x4 o[4] = {};

  const int kv0 = w * (N_TOK / WAVES);
  const int NIT = (N_TOK / WAVES) / KVB;   // 32

  short8 ka00, ka01, ka10, ka11, kb00, kb01, kb10, kb11;

#define LOAD_K(F0, F1, F2, F3, kvb) do {                                   \
    const short* kp_ = K + (size_t)((kvb) + lr) * D_OUT + g * 8;           \
    F0 = *reinterpret_cast<const short8*>(kp_);                            \
    F1 = *reinterpret_cast<const short8*>(kp_ + 32);                       \
    F2 = *reinterpret_cast<const short8*>(kp_ + 16 * D_OUT);               \
    F3 = *reinterpret_cast<const short8*>(kp_ + 16 * D_OUT + 32);          \
  } while (0)

  auto body = [&](short8 k00, short8 k01, short8 k10, short8 k11, int kvb) {
    // Vt A-frags (permuted k-slots): issue early, consumed last
    short8 av[4];
    #pragma unroll
    for (int dt = 0; dt < 4; ++dt) {
      const short* vp = Vt + (size_t)(dt * 16 + lr) * N_TOK + kvb + g * 4;
      short4v v0 = *reinterpret_cast<const short4v*>(vp);
      short4v v1 = *reinterpret_cast<const short4v*>(vp + 16);
      av[dt] = __builtin_shufflevector(v0, v1, 0, 1, 2, 3, 4, 5, 6, 7);
    }

    // S^T: s[jt][r] = S[kv = kvb + jt*16 + g*4 + r][q = lr]
    f32x4 s0 = {}, s1 = {};
    s0 = __builtin_amdgcn_mfma_f32_16x16x32_bf16(k00, aq0, s0, 0, 0, 0);
    s0 = __builtin_amdgcn_mfma_f32_16x16x32_bf16(k01, aq1, s0, 0, 0, 0);
    s1 = __builtin_amdgcn_mfma_f32_16x16x32_bf16(k10, aq0, s1, 0, 0, 0);
    s1 = __builtin_amdgcn_mfma_f32_16x16x32_bf16(k11, aq1, s1, 0, 0, 0);

    float lmax = fmaxf(fmaxf(fmaxf(s0[0], s0[1]), fmaxf(s0[2], s0[3])),
                       fmaxf(fmaxf(s1[0], s1[1]), fmaxf(s1[2], s1[3])));

    // defer-max (THR=8): cross-lane + rescale only when max grows
    if (!__all(lmax <= m + 8.0f)) {
      float wm = fmaxf(lmax, __shfl_xor(lmax, 16));
      wm = fmaxf(wm, __shfl_xor(wm, 32));
      const float mnew = fmaxf(m, wm);
      const float sc = __builtin_amdgcn_exp2f(m - mnew);  // first iter: 0
      #pragma unroll
      for (int dt = 0; dt < 4; ++dt) o[dt] *= sc;
      lsum *= sc;
      m = mnew;
    }

    float p00 = __builtin_amdgcn_exp2f(s0[0] - m);
    float p01 = __builtin_amdgcn_exp2f(s0[1] - m);
    float p02 = __builtin_amdgcn_exp2f(s0[2] - m);
    float p03 = __builtin_amdgcn_exp2f(s0[3] - m);
    float p10 = __builtin_amdgcn_exp2f(s1[0] - m);
    float p11 = __builtin_amdgcn_exp2f(s1[1] - m);
    float p12 = __builtin_amdgcn_exp2f(s1[2] - m);
    float p13 = __builtin_amdgcn_exp2f(s1[3] - m);
    lsum += ((p00 + p01) + (p02 + p03)) + ((p10 + p11) + (p12 + p13));

    // P registers -> PV B-frag directly (k-slot permutation), in-lane pack
    union { short8 s; unsigned u[4]; } pb;
    pb.u[0] = pack2(p00, p01);
    pb.u[1] = pack2(p02, p03);
    pb.u[2] = pack2(p10, p11);
    pb.u[3] = pack2(p12, p13);

    // O^T += Vt * P : o[dt][r] = O[d = dt*16 + g*4 + r][q = lr]
    #pragma unroll
    for (int dt = 0; dt < 4; ++dt)
      o[dt] = __builtin_amdgcn_mfma_f32_16x16x32_bf16(av[dt], pb.s, o[dt], 0, 0, 0);
  };

  LOAD_K(ka00, ka01, ka10, ka11, kv0);
  for (int it = 0; it < NIT; it += 2) {
    const int kvb0 = kv0 + it * KVB;
    LOAD_K(kb00, kb01, kb10, kb11, kvb0 + KVB);
    body(ka00, ka01, ka10, ka11, kvb0);
    if (it + 2 < NIT)
      LOAD_K(ka00, ka01, ka10, ka11, kvb0 + 2 * KVB);
    body(kb00, kb01, kb10, kb11, kvb0 + KVB);
  }
#undef LOAD_K

  // deferred l-sum reduce across the 4 lane-groups sharing each q
  lsum += __shfl_xor(lsum, 16);
  lsum += __shfl_xor(lsum, 32);

  // publish per-wave partials
  #pragma unroll
  for (int dt = 0; dt < 4; ++dt)
    *reinterpret_cast<f32x4*>(&Opart[w][lr][dt * 16 + g * 4]) = o[dt];
  if (l < 16) { mpart[w][l] = m; lpart[w][l] = lsum; }
  __syncthreads();

  // merge 8 wave partials; 512 threads cover 16x64 outputs in 2 passes
  for (int i = t; i < 16 * 64; i += 512) {
    const int qq = i >> 6, d = i & 63;
    float M = mpart[0][qq];
    #pragma unroll
    for (int w2 = 1; w2 < WAVES; ++w2) M = fmaxf(M, mpart[w2][qq]);
    float num = 0.0f, den = 0.0f;
    #pragma unroll
    for (int w2 = 0; w2 < WAVES; ++w2) {
      const float e = __builtin_amdgcn_exp2f(mpart[w2][qq] - M);
      num += e * Opart[w2][qq][d];
      den += e * lpart[w2][qq];
    }
    out[(size_t)(q0 + qq) * D_OUT + d] = num / den;
  }
}

extern "C" void kernel_launch(void* const* d_in, const int* in_sizes, int n_in,
                              void* d_out, int out_size, void* d_ws, size_t ws_size,
                              hipStream_t stream) {
  const float* X  = (const float*)d_in[0];
  const float* Wq = (const float*)d_in[1];
  const float* Wk = (const float*)d_in[2];
  const float* Wv = (const float*)d_in[3];

  short* Q  = (short*)d_ws;                       // [8192][64] bf16 (pre-scaled)
  short* K  = Q + (size_t)N_TOK * D_OUT;          // [8192][64] bf16
  short* Vt = K + (size_t)N_TOK * D_OUT;          // [64][8192] bf16
  float* out = (float*)d_out;

  hipLaunchKernelGGL(proj_kernel, dim3(N_TOK / 64, 3), dim3(256), 0, stream,
                     X, Wq, Wk, Wv, Q, K, Vt);
  hipLaunchKernelGGL(attn_kernel, dim3(N_TOK / 16), dim3(512), 0, stream,
                     Q, K, Vt, out);
}

// Round 5
// 63.826 us; speedup vs baseline: 3.0457x; 3.0457x over previous
//
#include <hip/hip_runtime.h>
#include <hip/hip_bf16.h>
#include <math.h>

#define N_TOK 8192
#define D_IN  768
#define D_OUT 64
#define KVB   64

typedef __attribute__((ext_vector_type(8))) short short8;
typedef __attribute__((ext_vector_type(4))) short short4v;
typedef __attribute__((ext_vector_type(4))) float f32x4;

// f32 -> bf16 bits, round-to-nearest-even
__device__ __forceinline__ short f2bf(float f) {
  union { float f; unsigned u; } v; v.f = f;
  unsigned r = v.u + 0x7fffu + ((v.u >> 16) & 1u);
  return (short)(r >> 16);
}
__device__ __forceinline__ unsigned pack2(float lo, float hi) {
  return (unsigned)(unsigned short)f2bf(lo) | ((unsigned)(unsigned short)f2bf(hi) << 16);
}

#define GLOAD16(SRC, DST) __builtin_amdgcn_global_load_lds(                  \
    (const __attribute__((address_space(1))) void*)(SRC),                    \
    (__attribute__((address_space(3))) void*)(DST), 16, 0, 0)

// ---------------------------------------------------------------------------
// Projection (R1 structure, measured ~11us): grid (N/64, 3).
//   which==0: Q, pre-scaled by log2(e)/8; which==1: K row-major;
//   which==2: V stored transposed AND slot-permuted: within each 32-kv block,
//   4-kv chunk c goes to slot-chunk (c<4 ? 2c : 2(c-4)+1), so attn's PV
//   A-fragments are contiguous 16B reads matching P's k-slot permutation.
// ---------------------------------------------------------------------------
__global__ __launch_bounds__(256) void proj_kernel(
    const float* __restrict__ X,
    const float* __restrict__ Wq, const float* __restrict__ Wk,
    const float* __restrict__ Wv,
    short* __restrict__ Q, short* __restrict__ K, short* __restrict__ Vp)
{
  __shared__ short Xs[64][40];
  __shared__ short Ws[64][40];   // W^T tile: [col][k]

  const int t  = threadIdx.x;
  const int w  = t >> 6;
  const int l  = t & 63;
  const int g  = l >> 4;
  const int lr = l & 15;
  const int which = blockIdx.y;
  const float* W = (which == 0) ? Wq : (which == 1) ? Wk : Wv;
  const int r0 = blockIdx.x * 64;

  f32x4 acc[4] = {};

  for (int kb = 0; kb < D_IN; kb += 32) {
    {
      const int row = t >> 2, kc = (t & 3) * 8;
      const float* src = X + (size_t)(r0 + row) * D_IN + kb + kc;
      short8 v;
      #pragma unroll
      for (int i = 0; i < 8; ++i) v[i] = f2bf(src[i]);
      *reinterpret_cast<short8*>(&Xs[row][kc]) = v;
    }
    {
      const int col = t & 63, k0 = (t >> 6) * 8;
      #pragma unroll
      for (int i = 0; i < 8; ++i)
        Ws[col][k0 + i] = f2bf(W[(size_t)(kb + k0 + i) * D_OUT + col]);
    }
    __syncthreads();

    short8 a = *reinterpret_cast<const short8*>(&Xs[w * 16 + lr][g * 8]);
    #pragma unroll
    for (int dt = 0; dt < 4; ++dt) {
      short8 b = *reinterpret_cast<const short8*>(&Ws[dt * 16 + lr][g * 8]);
      acc[dt] = __builtin_amdgcn_mfma_f32_16x16x32_bf16(a, b, acc[dt], 0, 0, 0);
    }
    __syncthreads();
  }

  const int rb = r0 + w * 16 + g * 4;
  if (which == 0) {
    const float QS = 0.18033688011112042f;  // log2(e) / sqrt(64)
    #pragma unroll
    for (int dt = 0; dt < 4; ++dt)
      #pragma unroll
      for (int r = 0; r < 4; ++r)
        Q[(size_t)(rb + r) * D_OUT + dt * 16 + lr] = f2bf(acc[dt][r] * QS);
  } else if (which == 1) {
    #pragma unroll
    for (int dt = 0; dt < 4; ++dt)
      #pragma unroll
      for (int r = 0; r < 4; ++r)
        K[(size_t)(rb + r) * D_OUT + dt * 16 + lr] = f2bf(acc[dt][r]);
  } else {
    // slot-permuted position for this 4-kv chunk
    const int c  = (rb >> 2) & 7;
    const int cp = (c < 4) ? (2 * c) : (2 * (c - 4) + 1);
    const int pos = (rb & ~31) + cp * 4;
    #pragma unroll
    for (int dt = 0; dt < 4; ++dt) {
      short4v pv;
      #pragma unroll
      for (int r = 0; r < 4; ++r) pv[r] = f2bf(acc[dt][r]);
      *reinterpret_cast<short4v*>(&Vp[(size_t)(dt * 16 + lr) * N_TOK + pos]) = pv;
    }
  }
}

// ---------------------------------------------------------------------------
// Flash attention, m214-style block structure:
//   block = 8 waves x 32 q-rows = 256 q, all sharing one KV stream.
//   KVB=64 K+V tiles staged in LDS (global_load_lds w16, double-buffered,
//   raw s_barrier + counted vmcnt(2), XOR-swizzle byte^=(row&7)<<4 applied
//   as pre-swizzled global source + swizzled ds_read).
//   Swapped MFMA: S=mfma(K,Q) -> lane holds S[kv regs][q=lane&15];
//   defer-max softmax (zero cross-lane steady state); P C-regs pack directly
//   to the PV B-frag via the k-slot permutation (V pre-permuted by proj).
//   grid = (N/256, S kv-splits); partials merged by merge_kernel.
// ---------------------------------------------------------------------------
__global__ __launch_bounds__(512, 4) void attn_kernel(
    const short* __restrict__ Qg, const short* __restrict__ Kg,
    const short* __restrict__ Vpg, float* __restrict__ Opart,
    float* __restrict__ mpart, float* __restrict__ lpart)
{
  __shared__ char smem[2][16384];   // [buf][ K 8KB | V 8KB ]

  const int t  = threadIdx.x;
  const int wq = t >> 6;            // wave 0..7 -> q-subtile
  const int l  = t & 63;
  const int g  = l >> 4;
  const int lr = l & 15;
  const int qb = blockIdx.x;
  const int s  = blockIdx.y;
  const int S  = gridDim.y;
  const int q0 = qb * 256 + wq * 32;
  const int kvlen = N_TOK / S;
  const int kv0 = s * kvlen;
  const int NT = kvlen / KVB;

  // Q B-fragments: aq[qt][kc], q = q0 + qt*16 + lr, d-chunk kc*32 + g*8
  short8 aq[2][2];
  #pragma unroll
  for (int qt = 0; qt < 2; ++qt)
    #pragma unroll
    for (int kc = 0; kc < 2; ++kc)
      aq[qt][kc] = *reinterpret_cast<const short8*>(
          Qg + (size_t)(q0 + qt * 16 + lr) * D_OUT + kc * 32 + g * 8);

  float m[2]  = {-INFINITY, -INFINITY};
  float ls[2] = {0.0f, 0.0f};
  f32x4 o[2][4] = {};

  // staging geometry: thread covers LDS offset t*16 of each 8KB tile
  const int o16  = t * 16;
  const int krow = o16 >> 7;                         // row 0..63
  const int ksw  = (o16 & 127) ^ ((krow & 7) << 4);  // pre-swizzled col bytes

  auto stage = [&](int tt, int b) {
    const int kvb = kv0 + tt * KVB;
    GLOAD16((const char*)Kg + ((size_t)(kvb + krow) * 128 + ksw),
            &smem[b][wq * 1024]);
    GLOAD16((const char*)Vpg + ((size_t)krow * (N_TOK * 2) + (size_t)kvb * 2 + ksw),
            &smem[b][8192 + wq * 1024]);
  };

  auto compute = [&](int b) {
    const char* KB = &smem[b][0];
    const char* VB = &smem[b][8192];

    // S phase: sc[qt][jt][r] = S[kv = jt*16 + g*4 + r][q]
    f32x4 sc[2][4];
    #pragma unroll
    for (int jt = 0; jt < 4; ++jt) {
      const int row = jt * 16 + lr;
      const int sw  = (row & 7) << 4;
      short8 k0 = *reinterpret_cast<const short8*>(KB + row * 128 + ((g * 16) ^ sw));
      short8 k1 = *reinterpret_cast<const short8*>(KB + row * 128 + ((64 + g * 16) ^ sw));
      f32x4 z = {};
      sc[0][jt] = __builtin_amdgcn_mfma_f32_16x16x32_bf16(k0, aq[0][0], z, 0, 0, 0);
      sc[0][jt] = __builtin_amdgcn_mfma_f32_16x16x32_bf16(k1, aq[0][1], sc[0][jt], 0, 0, 0);
      sc[1][jt] = __builtin_amdgcn_mfma_f32_16x16x32_bf16(k0, aq[1][0], z, 0, 0, 0);
      sc[1][jt] = __builtin_amdgcn_mfma_f32_16x16x32_bf16(k1, aq[1][1], sc[1][jt], 0, 0, 0);
    }

    // softmax (defer-max) + pack to PV B-frags
    short8 pb[2][2];
    #pragma unroll
    for (int qt = 0; qt < 2; ++qt) {
      float lmax = sc[qt][0][0];
      #pragma unroll
      for (int jt = 0; jt < 4; ++jt)
        #pragma unroll
        for (int r = 0; r < 4; ++r) lmax = fmaxf(lmax, sc[qt][jt][r]);
      if (!__all(lmax <= m[qt] + 8.0f)) {
        float wm = fmaxf(lmax, __shfl_xor(lmax, 16));
        wm = fmaxf(wm, __shfl_xor(wm, 32));
        const float mnew  = fmaxf(m[qt], wm);
        const float scale = __builtin_amdgcn_exp2f(m[qt] - mnew);  // first: 0
        #pragma unroll
        for (int dt = 0; dt < 4; ++dt) o[qt][dt] *= scale;
        ls[qt] *= scale;
        m[qt] = mnew;
      }
      float p[4][4]; float acc = 0.0f;
      #pragma unroll
      for (int jt = 0; jt < 4; ++jt)
        #pragma unroll
        for (int r = 0; r < 4; ++r) {
          p[jt][r] = __builtin_amdgcn_exp2f(sc[qt][jt][r] - m[qt]);
          acc += p[jt][r];
        }
      ls[qt] += acc;
      union { short8 v; unsigned u[4]; } b0, b1;
      b0.u[0] = pack2(p[0][0], p[0][1]); b0.u[1] = pack2(p[0][2], p[0][3]);
      b0.u[2] = pack2(p[1][0], p[1][1]); b0.u[3] = pack2(p[1][2], p[1][3]);
      b1.u[0] = pack2(p[2][0], p[2][1]); b1.u[1] = pack2(p[2][2], p[2][3]);
      b1.u[2] = pack2(p[3][0], p[3][1]); b1.u[3] = pack2(p[3][2], p[3][3]);
      pb[qt][0] = b0.v; pb[qt][1] = b1.v;
    }

    // PV phase: o[qt][dt][r] = O[d = dt*16 + g*4 + r][q]
    #pragma unroll
    for (int dt = 0; dt < 4; ++dt) {
      const int row = dt * 16 + lr;
      const int sw  = (row & 7) << 4;
      short8 v0 = *reinterpret_cast<const short8*>(VB + row * 128 + ((g * 16) ^ sw));
      short8 v1 = *reinterpret_cast<const short8*>(VB + row * 128 + ((64 + g * 16) ^ sw));
      #pragma unroll
      for (int qt = 0; qt < 2; ++qt) {
        o[qt][dt] = __builtin_amdgcn_mfma_f32_16x16x32_bf16(v0, pb[qt][0], o[qt][dt], 0, 0, 0);
        o[qt][dt] = __builtin_amdgcn_mfma_f32_16x16x32_bf16(v1, pb[qt][1], o[qt][dt], 0, 0, 0);
      }
    }
  };

  stage(0, 0);
  for (int tt = 0; tt < NT; ++tt) {
    if (tt + 1 < NT) {
      stage(tt + 1, (tt + 1) & 1);
      asm volatile("s_waitcnt vmcnt(2)" ::: "memory");   // drain tile tt only
    } else {
      asm volatile("s_waitcnt vmcnt(0)" ::: "memory");
    }
    __builtin_amdgcn_s_barrier();
    compute(tt & 1);
    __builtin_amdgcn_s_barrier();
  }

  // epilogue: reduce l across the 4 g-groups, publish per-(split,q) partials
  #pragma unroll
  for (int qt = 0; qt < 2; ++qt) {
    ls[qt] += __shfl_xor(ls[qt], 16);
    ls[qt] += __shfl_xor(ls[qt], 32);
    const int q = q0 + qt * 16 + lr;
    float* op = Opart + ((size_t)s * N_TOK + q) * D_OUT;
    #pragma unroll
    for (int dt = 0; dt < 4; ++dt)
      *reinterpret_cast<f32x4*>(op + dt * 16 + g * 4) = o[qt][dt];
    if (g == 0) {
      mpart[(size_t)s * N_TOK + q] = m[qt];
      lpart[(size_t)s * N_TOK + q] = ls[qt];
    }
  }
}

// ---------------------------------------------------------------------------
// Merge S kv-split partials: out[q][d] = sum_s e_s*O_s / sum_s e_s*l_s
// ---------------------------------------------------------------------------
__global__ __launch_bounds__(256) void merge_kernel(
    const float* __restrict__ Opart, const float* __restrict__ mpart,
    const float* __restrict__ lpart, float* __restrict__ out, int S)
{
  const int i = blockIdx.x * 256 + threadIdx.x;   // q*64 + d
  const int q = i >> 6;
  float M = -INFINITY;
  for (int s2 = 0; s2 < S; ++s2) M = fmaxf(M, mpart[(size_t)s2 * N_TOK + q]);
  float num = 0.0f, den = 0.0f;
  for (int s2 = 0; s2 < S; ++s2) {
    const float e = __builtin_amdgcn_exp2f(mpart[(size_t)s2 * N_TOK + q] - M);
    num += e * Opart[(size_t)s2 * ((size_t)N_TOK * D_OUT) + i];
    den += e * lpart[(size_t)s2 * N_TOK + q];
  }
  out[i] = num / den;
}

extern "C" void kernel_launch(void* const* d_in, const int* in_sizes, int n_in,
                              void* d_out, int out_size, void* d_ws, size_t ws_size,
                              hipStream_t stream) {
  const float* X  = (const float*)d_in[0];
  const float* Wq = (const float*)d_in[1];
  const float* Wk = (const float*)d_in[2];
  const float* Wv = (const float*)d_in[3];

  const size_t PROJ = (size_t)N_TOK * D_OUT;
  short* Q  = (short*)d_ws;            // [8192][64] bf16 (pre-scaled)
  short* Kb = Q + PROJ;                // [8192][64] bf16
  short* Vp = Kb + PROJ;               // [64][8192] bf16, slot-permuted
  float* fbase = (float*)(Vp + PROJ);

  // choose kv-split count S by available workspace (deterministic in ws_size)
  int S = 16;
  while (S > 1) {
    const size_t need = PROJ * 2 * 3 +
                        (size_t)S * N_TOK * (D_OUT + 2) * sizeof(float);
    if (need <= ws_size) break;
    S >>= 1;
  }
  float* Opart = fbase;                               // [S][8192][64]
  float* mpart = Opart + (size_t)S * N_TOK * D_OUT;   // [S][8192]
  float* lpart = mpart + (size_t)S * N_TOK;           // [S][8192]
  float* out   = (float*)d_out;

  hipLaunchKernelGGL(proj_kernel, dim3(N_TOK / 64, 3), dim3(256), 0, stream,
                     X, Wq, Wk, Wv, Q, Kb, Vp);
  hipLaunchKernelGGL(attn_kernel, dim3(N_TOK / 256, S), dim3(512), 0, stream,
                     Q, Kb, Vp, Opart, mpart, lpart);
  hipLaunchKernelGGL(merge_kernel, dim3(N_TOK * D_OUT / 256), dim3(256), 0, stream,
                     Opart, mpart, lpart, out, S);
}

// Round 6
// 57.003 us; speedup vs baseline: 3.4103x; 1.1197x over previous
//
#include <hip/hip_runtime.h>
#include <hip/hip_bf16.h>
#include <math.h>

#define N_TOK 8192
#define D_IN  768
#define D_OUT 64
#define KVB   64

typedef __attribute__((ext_vector_type(8))) short short8;
typedef __attribute__((ext_vector_type(4))) short short4v;
typedef __attribute__((ext_vector_type(4))) float f32x4;

// f32 -> bf16 bits, round-to-nearest-even (host-side-ish helper for proj)
__device__ __forceinline__ short f2bf(float f) {
  union { float f; unsigned u; } v; v.f = f;
  unsigned r = v.u + 0x7fffu + ((v.u >> 16) & 1u);
  return (short)(r >> 16);
}
// packed f32x2 -> bf16x2, single instruction (T12 recipe; no builtin on gfx950)
__device__ __forceinline__ unsigned cvtpk(float lo, float hi) {
  unsigned r;
  asm("v_cvt_pk_bf16_f32 %0, %1, %2" : "=v"(r) : "v"(lo), "v"(hi));
  return r;
}

#define GLOAD16(SRC, DST) __builtin_amdgcn_global_load_lds(                  \
    (const __attribute__((address_space(1))) void*)(SRC),                    \
    (__attribute__((address_space(3))) void*)(DST), 16, 0, 0)

// ---------------------------------------------------------------------------
// Projection: grid (N/64, 3).
//   which==0: Q, pre-scaled by log2(e)/8; which==1: K row-major;
//   which==2: V transposed AND slot-permuted (4-kv chunk c -> c<4?2c:2(c-4)+1
//   within each 32-kv block) so attn's PV A-frags match P's k-slot order.
// ---------------------------------------------------------------------------
__global__ __launch_bounds__(256) void proj_kernel(
    const float* __restrict__ X,
    const float* __restrict__ Wq, const float* __restrict__ Wk,
    const float* __restrict__ Wv,
    short* __restrict__ Q, short* __restrict__ K, short* __restrict__ Vp)
{
  __shared__ short Xs[64][40];
  __shared__ short Ws[64][40];   // W^T tile: [col][k]

  const int t  = threadIdx.x;
  const int w  = t >> 6;
  const int l  = t & 63;
  const int g  = l >> 4;
  const int lr = l & 15;
  const int which = blockIdx.y;
  const float* W = (which == 0) ? Wq : (which == 1) ? Wk : Wv;
  const int r0 = blockIdx.x * 64;

  f32x4 acc[4] = {};

  for (int kb = 0; kb < D_IN; kb += 32) {
    {
      const int row = t >> 2, kc = (t & 3) * 8;
      const float* src = X + (size_t)(r0 + row) * D_IN + kb + kc;
      short8 v;
      #pragma unroll
      for (int i = 0; i < 8; ++i) v[i] = f2bf(src[i]);
      *reinterpret_cast<short8*>(&Xs[row][kc]) = v;
    }
    {
      const int col = t & 63, k0 = (t >> 6) * 8;
      #pragma unroll
      for (int i = 0; i < 8; ++i)
        Ws[col][k0 + i] = f2bf(W[(size_t)(kb + k0 + i) * D_OUT + col]);
    }
    __syncthreads();

    short8 a = *reinterpret_cast<const short8*>(&Xs[w * 16 + lr][g * 8]);
    #pragma unroll
    for (int dt = 0; dt < 4; ++dt) {
      short8 b = *reinterpret_cast<const short8*>(&Ws[dt * 16 + lr][g * 8]);
      acc[dt] = __builtin_amdgcn_mfma_f32_16x16x32_bf16(a, b, acc[dt], 0, 0, 0);
    }
    __syncthreads();
  }

  const int rb = r0 + w * 16 + g * 4;
  if (which == 0) {
    const float QS = 0.18033688011112042f;  // log2(e) / sqrt(64)
    #pragma unroll
    for (int dt = 0; dt < 4; ++dt)
      #pragma unroll
      for (int r = 0; r < 4; ++r)
        Q[(size_t)(rb + r) * D_OUT + dt * 16 + lr] = f2bf(acc[dt][r] * QS);
  } else if (which == 1) {
    #pragma unroll
    for (int dt = 0; dt < 4; ++dt)
      #pragma unroll
      for (int r = 0; r < 4; ++r)
        K[(size_t)(rb + r) * D_OUT + dt * 16 + lr] = f2bf(acc[dt][r]);
  } else {
    const int c  = (rb >> 2) & 7;
    const int cp = (c < 4) ? (2 * c) : (2 * (c - 4) + 1);
    const int pos = (rb & ~31) + cp * 4;
    #pragma unroll
    for (int dt = 0; dt < 4; ++dt) {
      short4v pv;
      #pragma unroll
      for (int r = 0; r < 4; ++r) pv[r] = f2bf(acc[dt][r]);
      *reinterpret_cast<short4v*>(&Vp[(size_t)(dt * 16 + lr) * N_TOK + pos]) = pv;
    }
  }
}

// ---------------------------------------------------------------------------
// Flash attention: block = 8 waves x 16 q = 128 q-rows sharing one KV stream.
//   KVB=64 K+V tiles in LDS (global_load_lds w16, double-buffered, raw
//   s_barrier + counted vmcnt(2), XOR-swizzle byte^=(row&7)<<4 via
//   pre-swizzled global source + swizzled ds_read).
//   S = mfma(K,Q): lane holds S[kv regs][q = lane&15]; defer-max softmax;
//   P C-regs -> PV B-frag via k-slot permutation + v_cvt_pk_bf16_f32.
//   grid = (N/128, S kv-splits); partials merged by merge_kernel.
// ---------------------------------------------------------------------------
__global__ __launch_bounds__(512, 4) void attn_kernel(
    const short* __restrict__ Qg, const short* __restrict__ Kg,
    const short* __restrict__ Vpg, float* __restrict__ Opart,
    float* __restrict__ mpart, float* __restrict__ lpart)
{
  __shared__ char smem[2][16384];   // [buf][ K 8KB | V 8KB ]

  const int t  = threadIdx.x;
  const int wq = t >> 6;            // wave 0..7 -> q-subtile
  const int l  = t & 63;
  const int g  = l >> 4;
  const int lr = l & 15;
  const int s  = blockIdx.y;
  const int S  = gridDim.y;
  const int q0 = blockIdx.x * 128 + wq * 16;
  const int kvlen = N_TOK / S;
  const int kv0 = s * kvlen;
  const int NT = kvlen / KVB;

  // Q B-fragments: aq[kc], q = q0 + lr, d-chunk kc*32 + g*8
  short8 aq[2];
  #pragma unroll
  for (int kc = 0; kc < 2; ++kc)
    aq[kc] = *reinterpret_cast<const short8*>(
        Qg + (size_t)(q0 + lr) * D_OUT + kc * 32 + g * 8);

  float m = -INFINITY, ls = 0.0f;
  f32x4 o[4] = {};

  // staging geometry: thread covers LDS offset t*16 of each 8KB tile
  const int o16  = t * 16;
  const int krow = o16 >> 7;                         // row 0..63
  const int ksw  = (o16 & 127) ^ ((krow & 7) << 4);  // pre-swizzled col bytes

  auto stage = [&](int tt, int b) {
    const int kvb = kv0 + tt * KVB;
    GLOAD16((const char*)Kg + ((size_t)(kvb + krow) * 128 + ksw),
            &smem[b][wq * 1024]);
    GLOAD16((const char*)Vpg + ((size_t)krow * (N_TOK * 2) + (size_t)kvb * 2 + ksw),
            &smem[b][8192 + wq * 1024]);
  };

  auto compute = [&](int b) {
    const char* KB = &smem[b][0];
    const char* VB = &smem[b][8192];

    // S phase: sc[jt][r] = S[kv = jt*16 + g*4 + r][q]
    f32x4 sc[4];
    #pragma unroll
    for (int jt = 0; jt < 4; ++jt) {
      const int row = jt * 16 + lr;
      const int sw  = (row & 7) << 4;
      short8 k0 = *reinterpret_cast<const short8*>(KB + row * 128 + ((g * 16) ^ sw));
      short8 k1 = *reinterpret_cast<const short8*>(KB + row * 128 + ((64 + g * 16) ^ sw));
      f32x4 z = {};
      sc[jt] = __builtin_amdgcn_mfma_f32_16x16x32_bf16(k0, aq[0], z, 0, 0, 0);
      sc[jt] = __builtin_amdgcn_mfma_f32_16x16x32_bf16(k1, aq[1], sc[jt], 0, 0, 0);
    }

    // softmax (defer-max), zero cross-lane steady state
    float lmax = fmaxf(
        fmaxf(fmaxf(fmaxf(sc[0][0], sc[0][1]), fmaxf(sc[0][2], sc[0][3])),
              fmaxf(fmaxf(sc[1][0], sc[1][1]), fmaxf(sc[1][2], sc[1][3]))),
        fmaxf(fmaxf(fmaxf(sc[2][0], sc[2][1]), fmaxf(sc[2][2], sc[2][3])),
              fmaxf(fmaxf(sc[3][0], sc[3][1]), fmaxf(sc[3][2], sc[3][3]))));
    if (!__all(lmax <= m + 8.0f)) {
      float wm = fmaxf(lmax, __shfl_xor(lmax, 16));
      wm = fmaxf(wm, __shfl_xor(wm, 32));
      const float mnew  = fmaxf(m, wm);
      const float scale = __builtin_amdgcn_exp2f(m - mnew);  // first: 0
      #pragma unroll
      for (int dt = 0; dt < 4; ++dt) o[dt] *= scale;
      ls *= scale;
      m = mnew;
    }
    float p[4][4];
    float acc = 0.0f;
    #pragma unroll
    for (int jt = 0; jt < 4; ++jt)
      #pragma unroll
      for (int r = 0; r < 4; ++r) {
        p[jt][r] = __builtin_amdgcn_exp2f(sc[jt][r] - m);
        acc += p[jt][r];
      }
    ls += acc;

    // P -> PV B-frags via k-slot permutation + packed bf16 convert
    union { short8 v; unsigned u[4]; } b0, b1;
    b0.u[0] = cvtpk(p[0][0], p[0][1]); b0.u[1] = cvtpk(p[0][2], p[0][3]);
    b0.u[2] = cvtpk(p[1][0], p[1][1]); b0.u[3] = cvtpk(p[1][2], p[1][3]);
    b1.u[0] = cvtpk(p[2][0], p[2][1]); b1.u[1] = cvtpk(p[2][2], p[2][3]);
    b1.u[2] = cvtpk(p[3][0], p[3][1]); b1.u[3] = cvtpk(p[3][2], p[3][3]);

    // PV phase: o[dt][r] = O[d = dt*16 + g*4 + r][q]
    #pragma unroll
    for (int dt = 0; dt < 4; ++dt) {
      const int row = dt * 16 + lr;
      const int sw  = (row & 7) << 4;
      short8 v0 = *reinterpret_cast<const short8*>(VB + row * 128 + ((g * 16) ^ sw));
      short8 v1 = *reinterpret_cast<const short8*>(VB + row * 128 + ((64 + g * 16) ^ sw));
      o[dt] = __builtin_amdgcn_mfma_f32_16x16x32_bf16(v0, b0.v, o[dt], 0, 0, 0);
      o[dt] = __builtin_amdgcn_mfma_f32_16x16x32_bf16(v1, b1.v, o[dt], 0, 0, 0);
    }
  };

  stage(0, 0);
  for (int tt = 0; tt < NT; ++tt) {
    if (tt + 1 < NT) {
      stage(tt + 1, (tt + 1) & 1);
      asm volatile("s_waitcnt vmcnt(2)" ::: "memory");   // drain tile tt only
    } else {
      asm volatile("s_waitcnt vmcnt(0)" ::: "memory");
    }
    __builtin_amdgcn_s_barrier();
    compute(tt & 1);
    __builtin_amdgcn_s_barrier();
  }

  // epilogue: reduce l across the 4 g-groups, publish per-(split,q) partials
  ls += __shfl_xor(ls, 16);
  ls += __shfl_xor(ls, 32);
  const int q = q0 + lr;
  float* op = Opart + ((size_t)s * N_TOK + q) * D_OUT;
  #pragma unroll
  for (int dt = 0; dt < 4; ++dt)
    *reinterpret_cast<f32x4*>(op + dt * 16 + g * 4) = o[dt];
  if (g == 0) {
    mpart[(size_t)s * N_TOK + q] = m;
    lpart[(size_t)s * N_TOK + q] = ls;
  }
}

// ---------------------------------------------------------------------------
// Merge S kv-split partials: out[q][d] = sum_s e_s*O_s / sum_s e_s*l_s
// ---------------------------------------------------------------------------
__global__ __launch_bounds__(256) void merge_kernel(
    const float* __restrict__ Opart, const float* __restrict__ mpart,
    const float* __restrict__ lpart, float* __restrict__ out, int S)
{
  const int i = blockIdx.x * 256 + threadIdx.x;   // q*64 + d
  const int q = i >> 6;
  float M = -INFINITY;
  for (int s2 = 0; s2 < S; ++s2) M = fmaxf(M, mpart[(size_t)s2 * N_TOK + q]);
  float num = 0.0f, den = 0.0f;
  for (int s2 = 0; s2 < S; ++s2) {
    const float e = __builtin_amdgcn_exp2f(mpart[(size_t)s2 * N_TOK + q] - M);
    num += e * Opart[(size_t)s2 * ((size_t)N_TOK * D_OUT) + i];
    den += e * lpart[(size_t)s2 * N_TOK + q];
  }
  out[i] = num / den;
}

extern "C" void kernel_launch(void* const* d_in, const int* in_sizes, int n_in,
                              void* d_out, int out_size, void* d_ws, size_t ws_size,
                              hipStream_t stream) {
  const float* X  = (const float*)d_in[0];
  const float* Wq = (const float*)d_in[1];
  const float* Wk = (const float*)d_in[2];
  const float* Wv = (const float*)d_in[3];

  const size_t PROJ = (size_t)N_TOK * D_OUT;
  short* Q  = (short*)d_ws;            // [8192][64] bf16 (pre-scaled)
  short* Kb = Q + PROJ;                // [8192][64] bf16
  short* Vp = Kb + PROJ;               // [64][8192] bf16, slot-permuted
  float* fbase = (float*)(Vp + PROJ);

  // kv-split count S, capped by available workspace (deterministic)
  int S = 8;
  while (S > 1) {
    const size_t need = PROJ * 2 * 3 +
                        (size_t)S * N_TOK * (D_OUT + 2) * sizeof(float);
    if (need <= ws_size) break;
    S >>= 1;
  }
  float* Opart = fbase;                               // [S][8192][64]
  float* mpart = Opart + (size_t)S * N_TOK * D_OUT;   // [S][8192]
  float* lpart = mpart + (size_t)S * N_TOK;           // [S][8192]
  float* out   = (float*)d_out;

  hipLaunchKernelGGL(proj_kernel, dim3(N_TOK / 64, 3), dim3(256), 0, stream,
                     X, Wq, Wk, Wv, Q, Kb, Vp);
  hipLaunchKernelGGL(attn_kernel, dim3(N_TOK / 128, S), dim3(512), 0, stream,
                     Q, Kb, Vp, Opart, mpart, lpart);
  hipLaunchKernelGGL(merge_kernel, dim3(N_TOK * D_OUT / 256), dim3(256), 0, stream,
                     Opart, mpart, lpart, out, S);
}

// Round 8
// 56.118 us; speedup vs baseline: 3.4641x; 1.0158x over previous
//
#include <hip/hip_runtime.h>
#include <hip/hip_bf16.h>
#include <math.h>

#define N_TOK 8192
#define D_IN  768
#define D_OUT 64
#define KVB   64

typedef __attribute__((ext_vector_type(8))) short short8;
typedef __attribute__((ext_vector_type(4))) short short4v;
typedef __attribute__((ext_vector_type(4))) float f32x4;

// f32 -> bf16 bits, round-to-nearest-even
__device__ __forceinline__ short f2bf(float f) {
  union { float f; unsigned u; } v; v.f = f;
  unsigned r = v.u + 0x7fffu + ((v.u >> 16) & 1u);
  return (short)(r >> 16);
}
// packed f32x2 -> bf16x2, single instruction (T12 recipe)
__device__ __forceinline__ unsigned cvtpk(float lo, float hi) {
  unsigned r;
  asm("v_cvt_pk_bf16_f32 %0, %1, %2" : "=v"(r) : "v"(lo), "v"(hi));
  return r;
}

#define GLOAD16(SRC, DST) __builtin_amdgcn_global_load_lds(                  \
    (const __attribute__((address_space(1))) void*)(SRC),                    \
    (__attribute__((address_space(3))) void*)(DST), 16, 0, 0)

// ---------------------------------------------------------------------------
// Projection: grid (N/64, 3).
//   which==0: Q, pre-scaled by log2(e)/8; which==1: K row-major;
//   which==2: V transposed AND slot-permuted (4-kv chunk c -> c<4?2c:2(c-4)+1
//   within each 32-kv block) so attn's PV A-frags match P's k-slot order.
// ---------------------------------------------------------------------------
__global__ __launch_bounds__(256) void proj_kernel(
    const float* __restrict__ X,
    const float* __restrict__ Wq, const float* __restrict__ Wk,
    const float* __restrict__ Wv,
    short* __restrict__ Q, short* __restrict__ K, short* __restrict__ Vp)
{
  __shared__ short Xs[64][40];
  __shared__ short Ws[64][40];   // W^T tile: [col][k]

  const int t  = threadIdx.x;
  const int w  = t >> 6;
  const int l  = t & 63;
  const int g  = l >> 4;
  const int lr = l & 15;
  const int which = blockIdx.y;
  const float* W = (which == 0) ? Wq : (which == 1) ? Wk : Wv;
  const int r0 = blockIdx.x * 64;

  f32x4 acc[4] = {};

  for (int kb = 0; kb < D_IN; kb += 32) {
    {
      const int row = t >> 2, kc = (t & 3) * 8;
      const float* src = X + (size_t)(r0 + row) * D_IN + kb + kc;
      short8 v;
      #pragma unroll
      for (int i = 0; i < 8; ++i) v[i] = f2bf(src[i]);
      *reinterpret_cast<short8*>(&Xs[row][kc]) = v;
    }
    {
      const int col = t & 63, k0 = (t >> 6) * 8;
      #pragma unroll
      for (int i = 0; i < 8; ++i)
        Ws[col][k0 + i] = f2bf(W[(size_t)(kb + k0 + i) * D_OUT + col]);
    }
    __syncthreads();

    short8 a = *reinterpret_cast<const short8*>(&Xs[w * 16 + lr][g * 8]);
    #pragma unroll
    for (int dt = 0; dt < 4; ++dt) {
      short8 b = *reinterpret_cast<const short8*>(&Ws[dt * 16 + lr][g * 8]);
      acc[dt] = __builtin_amdgcn_mfma_f32_16x16x32_bf16(a, b, acc[dt], 0, 0, 0);
    }
    __syncthreads();
  }

  const int rb = r0 + w * 16 + g * 4;
  if (which == 0) {
    const float QS = 0.18033688011112042f;  // log2(e) / sqrt(64)
    #pragma unroll
    for (int dt = 0; dt < 4; ++dt)
      #pragma unroll
      for (int r = 0; r < 4; ++r)
        Q[(size_t)(rb + r) * D_OUT + dt * 16 + lr] = f2bf(acc[dt][r] * QS);
  } else if (which == 1) {
    #pragma unroll
    for (int dt = 0; dt < 4; ++dt)
      #pragma unroll
      for (int r = 0; r < 4; ++r)
        K[(size_t)(rb + r) * D_OUT + dt * 16 + lr] = f2bf(acc[dt][r]);
  } else {
    const int c  = (rb >> 2) & 7;
    const int cp = (c < 4) ? (2 * c) : (2 * (c - 4) + 1);
    const int pos = (rb & ~31) + cp * 4;
    #pragma unroll
    for (int dt = 0; dt < 4; ++dt) {
      short4v pv;
      #pragma unroll
      for (int r = 0; r < 4; ++r) pv[r] = f2bf(acc[dt][r]);
      *reinterpret_cast<short4v*>(&Vp[(size_t)(dt * 16 + lr) * N_TOK + pos]) = pv;
    }
  }
}

// ---------------------------------------------------------------------------
// Flash attention with lag-1 PV pipeline:
//   block = 8 waves x 16 q = 128 q-rows sharing one KV stream.
//   K, V each double-buffered in LDS (global_load_lds w16, XOR-swizzle,
//   counted vmcnt, raw s_barrier). Phase t: issue QK(t) + PV(t-1) MFMAs
//   back-to-back (matrix pipe stays fed), then softmax(t) on the VALU.
//   Rescale of o happens after PV(t-1) is accumulated -> numerics exact.
//   P kept in registers (k-slot permutation + v_cvt_pk_bf16_f32).
//   grid = (N/128, S kv-splits); partials merged by merge_kernel.
// ---------------------------------------------------------------------------
__global__ __launch_bounds__(512, 4) void attn_kernel(
    const short* __restrict__ Qg, const short* __restrict__ Kg,
    const short* __restrict__ Vpg, float* __restrict__ Opart,
    float* __restrict__ mpart, float* __restrict__ lpart)
{
  __shared__ char smem[4][8192];   // [K0,K1,V0,V1]

  const int t  = threadIdx.x;
  const int wq = t >> 6;            // wave 0..7 -> q-subtile
  const int l  = t & 63;
  const int g  = l >> 4;
  const int lr = l & 15;
  const int s  = blockIdx.y;
  const int S  = gridDim.y;
  const int q0 = blockIdx.x * 128 + wq * 16;
  const int kvlen = N_TOK / S;
  const int kv0 = s * kvlen;
  const int NT = kvlen / KVB;

  // Q B-fragments: aq[kc], q = q0 + lr, d-chunk kc*32 + g*8
  short8 aq[2];
  #pragma unroll
  for (int kc = 0; kc < 2; ++kc)
    aq[kc] = *reinterpret_cast<const short8*>(
        Qg + (size_t)(q0 + lr) * D_OUT + kc * 32 + g * 8);

  float m = -INFINITY, ls = 0.0f;
  f32x4 o[4] = {};
  short8 pb0, pb1;                  // lag-1 P fragments (packed bf16)

  // staging geometry: thread covers LDS offset t*16 of each 8KB tile
  const int o16  = t * 16;
  const int krow = o16 >> 7;                         // row 0..63
  const int ksw  = (o16 & 127) ^ ((krow & 7) << 4);  // pre-swizzled col bytes

  auto stageK = [&](int tt, int b) {
    const int kvb = kv0 + tt * KVB;
    GLOAD16((const char*)Kg + ((size_t)(kvb + krow) * 128 + ksw),
            &smem[b][wq * 1024]);
  };
  auto stageV = [&](int tt, int b) {
    const int kvb = kv0 + tt * KVB;
    GLOAD16((const char*)Vpg + ((size_t)krow * (N_TOK * 2) + (size_t)kvb * 2 + ksw),
            &smem[2 + b][wq * 1024]);
  };

  // PV only (epilogue): o += V(vb) * pb
  auto pvOnly = [&](int vb) {
    const char* VB = &smem[2 + vb][0];
    __builtin_amdgcn_s_setprio(1);
    #pragma unroll
    for (int dt = 0; dt < 4; ++dt) {
      const int row = dt * 16 + lr;
      const int sw  = (row & 7) << 4;
      short8 v0 = *reinterpret_cast<const short8*>(VB + row * 128 + ((g * 16) ^ sw));
      short8 v1 = *reinterpret_cast<const short8*>(VB + row * 128 + ((64 + g * 16) ^ sw));
      o[dt] = __builtin_amdgcn_mfma_f32_16x16x32_bf16(v0, pb0, o[dt], 0, 0, 0);
      o[dt] = __builtin_amdgcn_mfma_f32_16x16x32_bf16(v1, pb1, o[dt], 0, 0, 0);
    }
    __builtin_amdgcn_s_setprio(0);
  };

  // phase t: QK(t) + PV(t-1) MFMAs, then softmax(t) + pack into pb
  auto compute = [&](int kb, int vb, bool hasPV) {
    const char* KB = &smem[kb][0];

    // QK: sc[jt][r] = S[kv = jt*16 + g*4 + r][q = lr]
    f32x4 sc[4];
    __builtin_amdgcn_s_setprio(1);
    #pragma unroll
    for (int jt = 0; jt < 4; ++jt) {
      const int row = jt * 16 + lr;
      const int sw  = (row & 7) << 4;
      short8 k0 = *reinterpret_cast<const short8*>(KB + row * 128 + ((g * 16) ^ sw));
      short8 k1 = *reinterpret_cast<const short8*>(KB + row * 128 + ((64 + g * 16) ^ sw));
      f32x4 z = {};
      sc[jt] = __builtin_amdgcn_mfma_f32_16x16x32_bf16(k0, aq[0], z, 0, 0, 0);
      sc[jt] = __builtin_amdgcn_mfma_f32_16x16x32_bf16(k1, aq[1], sc[jt], 0, 0, 0);
    }
    __builtin_amdgcn_s_setprio(0);

    if (hasPV) pvOnly(vb);   // independent of sc -> overlaps QK/softmax

    // softmax (defer-max); o-rescale reads o AFTER PV(t-1) accumulated
    float lmax = fmaxf(
        fmaxf(fmaxf(fmaxf(sc[0][0], sc[0][1]), fmaxf(sc[0][2], sc[0][3])),
              fmaxf(fmaxf(sc[1][0], sc[1][1]), fmaxf(sc[1][2], sc[1][3]))),
        fmaxf(fmaxf(fmaxf(sc[2][0], sc[2][1]), fmaxf(sc[2][2], sc[2][3])),
              fmaxf(fmaxf(sc[3][0], sc[3][1]), fmaxf(sc[3][2], sc[3][3]))));
    if (!__all(lmax <= m + 8.0f)) {
      float wm = fmaxf(lmax, __shfl_xor(lmax, 16));
      wm = fmaxf(wm, __shfl_xor(wm, 32));
      const float mnew  = fmaxf(m, wm);
      const float scale = __builtin_amdgcn_exp2f(m - mnew);  // first: 0
      #pragma unroll
      for (int dt = 0; dt < 4; ++dt) o[dt] *= scale;
      ls *= scale;
      m = mnew;
    }
    float p[4][4];
    float acc = 0.0f;
    #pragma unroll
    for (int jt = 0; jt < 4; ++jt)
      #pragma unroll
      for (int r = 0; r < 4; ++r) {
        p[jt][r] = __builtin_amdgcn_exp2f(sc[jt][r] - m);
        acc += p[jt][r];
      }
    ls += acc;

    union { short8 v; unsigned u[4]; } b0, b1;
    b0.u[0] = cvtpk(p[0][0], p[0][1]); b0.u[1] = cvtpk(p[0][2], p[0][3]);
    b0.u[2] = cvtpk(p[1][0], p[1][1]); b0.u[3] = cvtpk(p[1][2], p[1][3]);
    b1.u[0] = cvtpk(p[2][0], p[2][1]); b1.u[1] = cvtpk(p[2][2], p[2][3]);
    b1.u[2] = cvtpk(p[3][0], p[3][1]); b1.u[3] = cvtpk(p[3][2], p[3][3]);
    pb0 = b0.v; pb1 = b1.v;
  };

  stageK(0, 0);
  for (int tt = 0; tt < NT; ++tt) {
    if (tt + 1 < NT) {
      stageK(tt + 1, (tt + 1) & 1);
      stageV(tt, tt & 1);
      asm volatile("s_waitcnt vmcnt(2)" ::: "memory");  // K(t),V(t-1) landed
    } else {
      stageV(tt, tt & 1);
      asm volatile("s_waitcnt vmcnt(1)" ::: "memory");  // K(t),V(t-1) landed
    }
    __builtin_amdgcn_s_barrier();
    compute(tt & 1, (tt - 1) & 1, tt > 0);
    __builtin_amdgcn_s_barrier();
  }
  asm volatile("s_waitcnt vmcnt(0)" ::: "memory");      // V(NT-1) landed
  __builtin_amdgcn_s_barrier();
  pvOnly((NT - 1) & 1);                                 // final lagging PV

  // epilogue: reduce l across the 4 g-groups, publish per-(split,q) partials
  ls += __shfl_xor(ls, 16);
  ls += __shfl_xor(ls, 32);
  const int q = q0 + lr;
  float* op = Opart + ((size_t)s * N_TOK + q) * D_OUT;
  #pragma unroll
  for (int dt = 0; dt < 4; ++dt)
    *reinterpret_cast<f32x4*>(op + dt * 16 + g * 4) = o[dt];
  if (g == 0) {
    mpart[(size_t)s * N_TOK + q] = m;
    lpart[(size_t)s * N_TOK + q] = ls;
  }
}

// ---------------------------------------------------------------------------
// Merge S kv-split partials: out[q][d] = sum_s e_s*O_s / sum_s e_s*l_s
// ---------------------------------------------------------------------------
__global__ __launch_bounds__(256) void merge_kernel(
    const float* __restrict__ Opart, const float* __restrict__ mpart,
    const float* __restrict__ lpart, float* __restrict__ out, int S)
{
  const int i = blockIdx.x * 256 + threadIdx.x;   // q*64 + d
  const int q = i >> 6;
  float M = -INFINITY;
  for (int s2 = 0; s2 < S; ++s2) M = fmaxf(M, mpart[(size_t)s2 * N_TOK + q]);
  float num = 0.0f, den = 0.0f;
  for (int s2 = 0; s2 < S; ++s2) {
    const float e = __builtin_amdgcn_exp2f(mpart[(size_t)s2 * N_TOK + q] - M);
    num += e * Opart[(size_t)s2 * ((size_t)N_TOK * D_OUT) + i];
    den += e * lpart[(size_t)s2 * N_TOK + q];
  }
  out[i] = num / den;
}

extern "C" void kernel_launch(void* const* d_in, const int* in_sizes, int n_in,
                              void* d_out, int out_size, void* d_ws, size_t ws_size,
                              hipStream_t stream) {
  const float* X  = (const float*)d_in[0];
  const float* Wq = (const float*)d_in[1];
  const float* Wk = (const float*)d_in[2];
  const float* Wv = (const float*)d_in[3];

  const size_t PROJ = (size_t)N_TOK * D_OUT;
  short* Q  = (short*)d_ws;            // [8192][64] bf16 (pre-scaled)
  short* Kb = Q + PROJ;                // [8192][64] bf16
  short* Vp = Kb + PROJ;               // [64][8192] bf16, slot-permuted
  float* fbase = (float*)(Vp + PROJ);

  // kv-split count S, capped by available workspace (deterministic)
  int S = 8;
  while (S > 1) {
    const size_t need = PROJ * 2 * 3 +
                        (size_t)S * N_TOK * (D_OUT + 2) * sizeof(float);
    if (need <= ws_size) break;
    S >>= 1;
  }
  float* Opart = fbase;                               // [S][8192][64]
  float* mpart = Opart + (size_t)S * N_TOK * D_OUT;   // [S][8192]
  float* lpart = mpart + (size_t)S * N_TOK;           // [S][8192]
  float* out   = (float*)d_out;

  hipLaunchKernelGGL(proj_kernel, dim3(N_TOK / 64, 3), dim3(256), 0, stream,
                     X, Wq, Wk, Wv, Q, Kb, Vp);
  hipLaunchKernelGGL(attn_kernel, dim3(N_TOK / 128, S), dim3(512), 0, stream,
                     Q, Kb, Vp, Opart, mpart, lpart);
  hipLaunchKernelGGL(merge_kernel, dim3(N_TOK * D_OUT / 256), dim3(256), 0, stream,
                     Opart, mpart, lpart, out, S);
}